// Round 3
// baseline (1593.726 us; speedup 1.0000x reference)
//
#include <hip/hip_runtime.h>
#include <hip/hip_bf16.h>
#include <cstdint>
#include <cstddef>

#define D_DIM 1024
#define VOCAB 32000
#define ROWS  4096      // 16*256
#define KSPLIT2 5       // GEMM2 split-K: 32000/5 = 6400 per block = 100 BK-iters

typedef __attribute__((ext_vector_type(8))) short bf16x8;   // 8 bf16 = 4 VGPRs (MFMA A/B frag)
typedef __attribute__((ext_vector_type(4))) float f32x4;    // MFMA C/D frag

// float -> bf16 bits, round-to-nearest-even
static __device__ __forceinline__ unsigned short f2bf(float f) {
  union { float f; unsigned int u; } c; c.f = f;
  unsigned int u = c.u;
  u += 0x7fffu + ((u >> 16) & 1u);
  return (unsigned short)(u >> 16);
}

// async global->LDS, 16B per lane. LDS base must be wave-uniform; data lands at base + lane*16.
static __device__ __forceinline__ void gload_lds16(const void* g, void* s) {
  __builtin_amdgcn_global_load_lds(
      (const __attribute__((address_space(1))) uint32_t*)(g),
      (__attribute__((address_space(3))) uint32_t*)(s), 16, 0, 0);
}

// ---------------------------------------------------------------------------
// fp32 -> bf16 convert (4 elems/thread)
__global__ void k_cvt(const float* __restrict__ src, short* __restrict__ dst, int n4) {
  int i = blockIdx.x * 256 + threadIdx.x;
  if (i < n4) {
    float4 v = *(const float4*)(src + (size_t)i * 4);
    ushort4 u;
    u.x = f2bf(v.x); u.y = f2bf(v.y); u.z = f2bf(v.z); u.w = f2bf(v.w);
    *(ushort4*)(dst + (size_t)i * 4) = u;
  }
}

// ---------------------------------------------------------------------------
// tiled transpose: src[R][C] fp32 -> dst[C][R] bf16
__global__ void k_transpose(const float* __restrict__ src, short* __restrict__ dst,
                            int R, int C) {
  __shared__ float tile[32][33];
  int tx = threadIdx.x;           // 0..31
  int ty = threadIdx.y;           // 0..7
  int r0 = blockIdx.x * 32;
  int c0 = blockIdx.y * 32;
#pragma unroll
  for (int j = 0; j < 32; j += 8)
    tile[ty + j][tx] = src[(size_t)(r0 + ty + j) * C + c0 + tx];
  __syncthreads();
#pragma unroll
  for (int j = 0; j < 32; j += 8)
    dst[(size_t)(c0 + ty + j) * R + r0 + tx] = (short)f2bf(tile[tx][ty + j]);
}

// ---------------------------------------------------------------------------
// bf16 GEMM, C[M x N] = A[M x K_total] * B^T where B stored [N x K_total]
// (k-contiguous). Kdim = per-z-split K range; k0 = blockIdx.z * Kdim.
// 128x128 tile, BK=64, 256 threads (4 waves, each 64x64 via 4x4 of 16x16x32 MFMA).
// LDS tiles XOR-swizzled by 16B chunk: LDS[row][chunk j] = global chunk j^(row&7)
// -> fragment reads spread the wave over all 32 banks (2-way min aliasing = free).
// mode 0: Pout = exp(C) bf16 via LDS-transit coalesced 16B stores;
//         den[row] += rowsum(exp) (atomic)
// mode 1: num[row*1024+col] += C (fp32 atomicAdd; num pre-zeroed; split-K safe)
// mode 2: Cout = C + bias[col] + resid[row*1024+col]  (ldc = 1024)
#define PSTRIDE 136   // shorts; 272 B: multiple of 16 B (aligned b128) + bank spread
__global__ __launch_bounds__(256) void k_gemm(
    const short* __restrict__ A, int lda,
    const short* __restrict__ B, int ldb,
    int Kdim, int mode,
    short* __restrict__ Pout, long ldp, float* __restrict__ den,
    float* __restrict__ Cacc,
    const float* __restrict__ bias, const float* __restrict__ resid,
    float* __restrict__ Cout)
{
  // As: [0,8192) shorts, Bs: [8192,16384); mode-0 epilogue reuses whole region
  // as a 128 x PSTRIDE bf16 P-tile (needs 17408 shorts = 34 KiB).
  __shared__ short smem[17408];
  short* As = smem;
  short* Bs = smem + 8192;

  int tid  = threadIdx.x;
  int wave = tid >> 6;
  int lane = tid & 63;
  int quad = lane >> 4;
  int t16  = lane & 15;
  int wy = wave >> 1, wx = wave & 1;

  long mBase = (long)blockIdx.y * 128;
  long nBase = (long)blockIdx.x * 128;
  int  k0    = blockIdx.z * Kdim;

  const short* Ab = A + (size_t)mBase * lda + k0;
  const short* Bb = B + (size_t)nBase * ldb + k0;
  int lrow = lane >> 3;                      // 0..7
  int lcol = ((lane & 7) ^ lrow) * 8;        // swizzled source 16B-chunk

  f32x4 acc[4][4];
#pragma unroll
  for (int i = 0; i < 4; ++i)
#pragma unroll
    for (int j = 0; j < 4; ++j) acc[i][j] = (f32x4){0.f, 0.f, 0.f, 0.f};

  int sw = t16 & 7;                          // swizzle key for fragment reads

  for (int kk = 0; kk < Kdim; kk += 64) {
    // stage 128x64 A-tile and B-tile; each wave: 32 rows of each, 4 issues x 8 rows
#pragma unroll
    for (int i = 0; i < 4; ++i) {
      int row = wave * 32 + i * 8;
      gload_lds16(Ab + (size_t)(row + lrow) * lda + kk + lcol, &As[row * 64]);
      gload_lds16(Bb + (size_t)(row + lrow) * ldb + kk + lcol, &Bs[row * 64]);
    }
    __syncthreads();
#pragma unroll
    for (int kc = 0; kc < 8; kc += 4) {      // kc = base 16B-chunk (= ks/8), ks in {0,32}
      bf16x8 af[4], bfr[4];
#pragma unroll
      for (int mi = 0; mi < 4; ++mi)
        af[mi] = *(const bf16x8*)&As[(wy * 64 + mi * 16 + t16) * 64 +
                                     (((kc + quad) ^ sw) << 3)];
#pragma unroll
      for (int ni = 0; ni < 4; ++ni)
        bfr[ni] = *(const bf16x8*)&Bs[(wx * 64 + ni * 16 + t16) * 64 +
                                      (((kc + quad) ^ sw) << 3)];
#pragma unroll
      for (int mi = 0; mi < 4; ++mi)
#pragma unroll
        for (int ni = 0; ni < 4; ++ni)
          acc[mi][ni] = __builtin_amdgcn_mfma_f32_16x16x32_bf16(af[mi], bfr[ni],
                                                                acc[mi][ni], 0, 0, 0);
    }
    __syncthreads();
  }

  // epilogue. C/D layout: row = quad*4 + r, col = t16 (within 16x16 tile)
  if (mode == 0) {
    // exp -> bf16 P-tile in LDS, rowsum in regs
    float rsum[4][4];
#pragma unroll
    for (int mi = 0; mi < 4; ++mi)
#pragma unroll
      for (int r = 0; r < 4; ++r) rsum[mi][r] = 0.f;
#pragma unroll
    for (int mi = 0; mi < 4; ++mi) {
      int rloc = wy * 64 + mi * 16 + quad * 4;
#pragma unroll
      for (int ni = 0; ni < 4; ++ni) {
        int cloc = wx * 64 + ni * 16 + t16;
#pragma unroll
        for (int r = 0; r < 4; ++r) {
          float e = __expf(acc[mi][ni][r]);
          smem[(rloc + r) * PSTRIDE + cloc] = (short)f2bf(e);
          rsum[mi][r] += e;
        }
      }
    }
#pragma unroll
    for (int mi = 0; mi < 4; ++mi)
#pragma unroll
      for (int r = 0; r < 4; ++r) {
        float s = rsum[mi][r];
        s += __shfl_xor(s, 1);
        s += __shfl_xor(s, 2);
        s += __shfl_xor(s, 4);
        s += __shfl_xor(s, 8);
        if (t16 == 0)
          atomicAdd(&den[mBase + wy * 64 + mi * 16 + quad * 4 + r], s);
      }
    __syncthreads();
    // coalesced store: 8 iters x 256 thr x 16 B = 32 KB tile
    int rr = tid >> 4;            // 0..15
    int c8 = (tid & 15) * 8;      // 0..120
#pragma unroll
    for (int i = 0; i < 8; ++i) {
      int row = i * 16 + rr;
      bf16x8 v = *(const bf16x8*)&smem[row * PSTRIDE + c8];
      *(bf16x8*)&Pout[(size_t)(mBase + row) * ldp + nBase + c8] = v;
    }
  } else if (mode == 1) {
#pragma unroll
    for (int mi = 0; mi < 4; ++mi) {
      long row = mBase + wy * 64 + mi * 16 + quad * 4;
#pragma unroll
      for (int ni = 0; ni < 4; ++ni) {
        long col = nBase + wx * 64 + ni * 16 + t16;
#pragma unroll
        for (int r = 0; r < 4; ++r) {
          size_t idx = (size_t)(row + r) * 1024 + col;
          atomicAdd(&Cacc[idx], acc[mi][ni][r]);
        }
      }
    }
  } else {
#pragma unroll
    for (int mi = 0; mi < 4; ++mi) {
      long row = mBase + wy * 64 + mi * 16 + quad * 4;
#pragma unroll
      for (int ni = 0; ni < 4; ++ni) {
        long col = nBase + wx * 64 + ni * 16 + t16;
#pragma unroll
        for (int r = 0; r < 4; ++r) {
          size_t idx = (size_t)(row + r) * 1024 + col;
          Cout[idx] = acc[mi][ni][r] + bias[col] + resid[idx];
        }
      }
    }
  }
}

// ---------------------------------------------------------------------------
// reprog_bf16 = bf16(num / den[row]); 4 elems/thread, 4 | 1024 so row uniform
__global__ void k_div(const float* __restrict__ num, const float* __restrict__ den,
                      short* __restrict__ out) {
  int i = (blockIdx.x * 256 + threadIdx.x) * 4;
  float4 v = *(const float4*)(num + i);
  float inv = 1.0f / den[i >> 10];
  ushort4 u;
  u.x = f2bf(v.x * inv); u.y = f2bf(v.y * inv);
  u.z = f2bf(v.z * inv); u.w = f2bf(v.w * inv);
  *(ushort4*)(out + i) = u;
}

// ---------------------------------------------------------------------------
// per-row LayerNorm over 1024 cols; one block (256 thr) per row
__global__ __launch_bounds__(256) void k_ln(const float* __restrict__ x,
                                            const float* __restrict__ gamma,
                                            const float* __restrict__ beta,
                                            float* __restrict__ out) {
  __shared__ float s_sum[4], s_sq[4];
  int row = blockIdx.x;
  int tid = threadIdx.x;
  const float* xr = x + (size_t)row * 1024;
  float4 v = *(const float4*)(xr + tid * 4);
  float s = v.x + v.y + v.z + v.w;
  float q = v.x * v.x + v.y * v.y + v.z * v.z + v.w * v.w;
#pragma unroll
  for (int off = 32; off >= 1; off >>= 1) {
    s += __shfl_down(s, off);
    q += __shfl_down(q, off);
  }
  int wv = tid >> 6;
  if ((tid & 63) == 0) { s_sum[wv] = s; s_sq[wv] = q; }
  __syncthreads();
  float tot  = s_sum[0] + s_sum[1] + s_sum[2] + s_sum[3];
  float totq = s_sq[0] + s_sq[1] + s_sq[2] + s_sq[3];
  float mu   = tot * (1.0f / 1024.0f);
  float var  = totq * (1.0f / 1024.0f) - mu * mu;
  float rstd = rsqrtf(var + 1e-5f);
  float4 g = *(const float4*)(gamma + tid * 4);
  float4 b = *(const float4*)(beta + tid * 4);
  float4 o;
  o.x = (v.x - mu) * rstd * g.x + b.x;
  o.y = (v.y - mu) * rstd * g.y + b.y;
  o.z = (v.z - mu) * rstd * g.z + b.z;
  o.w = (v.w - mu) * rstd * g.w + b.w;
  *(float4*)(out + (size_t)row * 1024 + tid * 4) = o;
}

// ---------------------------------------------------------------------------
extern "C" void kernel_launch(void* const* d_in, const int* in_sizes, int n_in,
                              void* d_out, int out_size, void* d_ws, size_t ws_size,
                              hipStream_t stream) {
  const float* patch = (const float*)d_in[0];   // [16,256,1024] = [4096,1024]
  const float* proto = (const float*)d_in[1];   // [32000,1024]
  const float* W     = (const float*)d_in[2];   // [1024,1024] (e-major, d-contig)
  const float* bvec  = (const float*)d_in[3];   // [1024]
  const float* gamma = (const float*)d_in[4];   // [1024]
  const float* beta  = (const float*)d_in[5];   // [1024]
  float* out = (float*)d_out;

  // ws budget (harness poison fill showed ws_size = 500 MiB):
  char* ws = (char*)d_ws;
  size_t off = 0;
  short* Q   = (short*)(ws + off); off += (size_t)ROWS * D_DIM * 2;     //   8 MB bf16 Q
  short* Kb  = (short*)(ws + off); off += (size_t)VOCAB * D_DIM * 2;    //  64 MB bf16 K [v][d]
  short* KT  = (short*)(ws + off); off += (size_t)VOCAB * D_DIM * 2;    //  64 MB bf16 K^T [d][v]
  short* Wb  = (short*)(ws + off); off += (size_t)D_DIM * D_DIM * 2;    //   2 MB bf16 W
  short* P   = (short*)(ws + off); off += (size_t)ROWS * VOCAB * 2;     // 262 MB bf16 P (full)
  float* num = (float*)(ws + off); off += (size_t)ROWS * D_DIM * 4;     //  16 MB fp32 numerator
  float* den = (float*)(ws + off); off += (size_t)ROWS * 4;             //  16 KB fp32 denominator
  float* pre = (float*)P;   // reuse P region for pre-LN buffer
  short* Rb  = Q;           // reuse Q region for reprogrammed bf16

  hipMemsetAsync(den, 0, ROWS * sizeof(float), stream);
  hipMemsetAsync(num, 0, (size_t)ROWS * D_DIM * sizeof(float), stream);

  k_cvt<<<ROWS * D_DIM / 4 / 256, 256, 0, stream>>>(patch, Q, ROWS * D_DIM / 4);
  k_cvt<<<VOCAB * D_DIM / 4 / 256, 256, 0, stream>>>(proto, Kb, VOCAB * D_DIM / 4);
  k_cvt<<<D_DIM * D_DIM / 4 / 256, 256, 0, stream>>>(W, Wb, D_DIM * D_DIM / 4);
  k_transpose<<<dim3(VOCAB / 32, D_DIM / 32), dim3(32, 8), 0, stream>>>(proto, KT, VOCAB, D_DIM);

  // P = exp(Q @ K^T), den += rowsum — M=4096 N=32000 K=1024, one dispatch
  k_gemm<<<dim3(VOCAB / 128, ROWS / 128, 1), 256, 0, stream>>>(
      Q, D_DIM, Kb, D_DIM, D_DIM, 0,
      P, (long)VOCAB, den, nullptr, nullptr, nullptr, nullptr);

  // num += P @ K — M=4096 N=1024 K=32000, split-K=5 (100 BK-iters/block)
  k_gemm<<<dim3(D_DIM / 128, ROWS / 128, KSPLIT2), 256, 0, stream>>>(
      P, VOCAB, KT, VOCAB, VOCAB / KSPLIT2, 1,
      nullptr, 0, nullptr, num, nullptr, nullptr, nullptr);

  k_div<<<ROWS * D_DIM / 4 / 256, 256, 0, stream>>>(num, den, Rb);

  // pre = reprog @ W^T + b + patch — M=4096 N=1024 K=1024
  k_gemm<<<dim3(D_DIM / 128, ROWS / 128, 1), 256, 0, stream>>>(
      Rb, D_DIM, Wb, D_DIM, D_DIM, 2,
      nullptr, 0, nullptr, nullptr, bvec, patch, pre);

  k_ln<<<ROWS, 256, 0, stream>>>(pre, gamma, beta, out);
}

// Round 4
// 1189.519 us; speedup vs baseline: 1.3398x; 1.3398x over previous
//
#include <hip/hip_runtime.h>
#include <hip/hip_bf16.h>
#include <cstdint>
#include <cstddef>

#define D_DIM 1024
#define VOCAB 32000
#define ROWS  4096      // 16*256
#define KSPLIT2 5       // GEMM2 split-K: 32000/5 = 6400 per block = 100 BK-iters

typedef __attribute__((ext_vector_type(8))) short bf16x8;   // 8 bf16 = 4 VGPRs (MFMA A/B frag)
typedef __attribute__((ext_vector_type(4))) float f32x4;    // MFMA C/D frag

// float -> bf16 bits, round-to-nearest-even
static __device__ __forceinline__ unsigned short f2bf(float f) {
  union { float f; unsigned int u; } c; c.f = f;
  unsigned int u = c.u;
  u += 0x7fffu + ((u >> 16) & 1u);
  return (unsigned short)(u >> 16);
}

// async global->LDS, 16B per lane. LDS base must be wave-uniform; data lands at base + lane*16.
static __device__ __forceinline__ void gload_lds16(const void* g, void* s) {
  __builtin_amdgcn_global_load_lds(
      (const __attribute__((address_space(1))) uint32_t*)(g),
      (__attribute__((address_space(3))) uint32_t*)(s), 16, 0, 0);
}

// ---------------------------------------------------------------------------
// fp32 -> bf16 convert (4 elems/thread)
__global__ void k_cvt(const float* __restrict__ src, short* __restrict__ dst, int n4) {
  int i = blockIdx.x * 256 + threadIdx.x;
  if (i < n4) {
    float4 v = *(const float4*)(src + (size_t)i * 4);
    ushort4 u;
    u.x = f2bf(v.x); u.y = f2bf(v.y); u.z = f2bf(v.z); u.w = f2bf(v.w);
    *(ushort4*)(dst + (size_t)i * 4) = u;
  }
}

// ---------------------------------------------------------------------------
// fused: proto fp32 [R][C] -> Kb bf16 [R][C] AND KT bf16 [C][R] (one read pass)
__global__ void k_prep_K(const float* __restrict__ src, short* __restrict__ kb,
                         short* __restrict__ kt, int R, int C) {
  __shared__ short tile[32][33];
  int tx = threadIdx.x;           // 0..31
  int ty = threadIdx.y;           // 0..7
  int r0 = blockIdx.x * 32;
  int c0 = blockIdx.y * 32;
#pragma unroll
  for (int j = 0; j < 32; j += 8) {
    float v = src[(size_t)(r0 + ty + j) * C + c0 + tx];
    short b = (short)f2bf(v);
    kb[(size_t)(r0 + ty + j) * C + c0 + tx] = b;
    tile[ty + j][tx] = b;
  }
  __syncthreads();
#pragma unroll
  for (int j = 0; j < 32; j += 8)
    kt[(size_t)(c0 + ty + j) * R + r0 + tx] = tile[tx][ty + j];
}

// ---------------------------------------------------------------------------
// bf16 GEMM, C[M x N] = A[M x K_total] * B^T where B stored [N x K_total]
// (k-contiguous). Kdim = per-z-split K range; k0 = blockIdx.z * Kdim.
// 128x128 tile, BK=64, 256 threads (4 waves, each 64x64 via 4x4 of 16x16x32 MFMA).
// LDS tiles XOR-swizzled by 16B chunk: LDS[row][chunk j] = global chunk j^(row&7).
// mode 0: grid is (M-tiles fast, N-tiles slow) so concurrent blocks share Q and a
//         narrow K-stripe (L2/L3-resident); P written with NON-TEMPORAL stores so
//         the 262 MB stream doesn't evict K/Q from L3.
//         Pout = exp(C) bf16 via LDS-transit coalesced 16B nt-stores;
//         den[row] += rowsum(exp) (atomic)
// mode 1: num[row*1024+col] += C (fp32 atomicAdd; num pre-zeroed; split-K safe)
// mode 2: Cout = C + bias[col] + resid[row*1024+col]  (ldc = 1024)
#define PSTRIDE 136   // shorts; 272 B: multiple of 16 B (aligned b128) + bank spread
__global__ __launch_bounds__(256) void k_gemm(
    const short* __restrict__ A, int lda,
    const short* __restrict__ B, int ldb,
    int Kdim, int mode,
    short* __restrict__ Pout, long ldp, float* __restrict__ den,
    float* __restrict__ Cacc,
    const float* __restrict__ bias, const float* __restrict__ resid,
    float* __restrict__ Cout)
{
  // As: [0,8192) shorts, Bs: [8192,16384); mode-0 epilogue reuses whole region
  // as a 128 x PSTRIDE bf16 P-tile (needs 17408 shorts = 34 KiB).
  __shared__ short smem[17408];
  short* As = smem;
  short* Bs = smem + 8192;

  int tid  = threadIdx.x;
  int wave = tid >> 6;
  int lane = tid & 63;
  int quad = lane >> 4;
  int t16  = lane & 15;
  int wy = wave >> 1, wx = wave & 1;

  // mode 0: x = M-tile (fast) so concurrent blocks share B-stripe + all of Q
  long mBase, nBase;
  if (mode == 0) { mBase = (long)blockIdx.x * 128; nBase = (long)blockIdx.y * 128; }
  else           { mBase = (long)blockIdx.y * 128; nBase = (long)blockIdx.x * 128; }
  int k0 = blockIdx.z * Kdim;

  const short* Ab = A + (size_t)mBase * lda + k0;
  const short* Bb = B + (size_t)nBase * ldb + k0;
  int lrow = lane >> 3;                      // 0..7
  int lcol = ((lane & 7) ^ lrow) * 8;        // swizzled source 16B-chunk

  f32x4 acc[4][4];
#pragma unroll
  for (int i = 0; i < 4; ++i)
#pragma unroll
    for (int j = 0; j < 4; ++j) acc[i][j] = (f32x4){0.f, 0.f, 0.f, 0.f};

  int sw = t16 & 7;                          // swizzle key for fragment reads

  for (int kk = 0; kk < Kdim; kk += 64) {
    // stage 128x64 A-tile and B-tile; each wave: 32 rows of each, 4 issues x 8 rows
#pragma unroll
    for (int i = 0; i < 4; ++i) {
      int row = wave * 32 + i * 8;
      gload_lds16(Ab + (size_t)(row + lrow) * lda + kk + lcol, &As[row * 64]);
      gload_lds16(Bb + (size_t)(row + lrow) * ldb + kk + lcol, &Bs[row * 64]);
    }
    __syncthreads();
#pragma unroll
    for (int kc = 0; kc < 8; kc += 4) {      // kc = base 16B-chunk (= ks/8), ks in {0,32}
      bf16x8 af[4], bfr[4];
#pragma unroll
      for (int mi = 0; mi < 4; ++mi)
        af[mi] = *(const bf16x8*)&As[(wy * 64 + mi * 16 + t16) * 64 +
                                     (((kc + quad) ^ sw) << 3)];
#pragma unroll
      for (int ni = 0; ni < 4; ++ni)
        bfr[ni] = *(const bf16x8*)&Bs[(wx * 64 + ni * 16 + t16) * 64 +
                                      (((kc + quad) ^ sw) << 3)];
#pragma unroll
      for (int mi = 0; mi < 4; ++mi)
#pragma unroll
        for (int ni = 0; ni < 4; ++ni)
          acc[mi][ni] = __builtin_amdgcn_mfma_f32_16x16x32_bf16(af[mi], bfr[ni],
                                                                acc[mi][ni], 0, 0, 0);
    }
    __syncthreads();
  }

  // epilogue. C/D layout: row = quad*4 + r, col = t16 (within 16x16 tile)
  if (mode == 0) {
    // exp -> bf16 P-tile in LDS, rowsum in regs
    float rsum[4][4];
#pragma unroll
    for (int mi = 0; mi < 4; ++mi)
#pragma unroll
      for (int r = 0; r < 4; ++r) rsum[mi][r] = 0.f;
#pragma unroll
    for (int mi = 0; mi < 4; ++mi) {
      int rloc = wy * 64 + mi * 16 + quad * 4;
#pragma unroll
      for (int ni = 0; ni < 4; ++ni) {
        int cloc = wx * 64 + ni * 16 + t16;
#pragma unroll
        for (int r = 0; r < 4; ++r) {
          float e = __expf(acc[mi][ni][r]);
          smem[(rloc + r) * PSTRIDE + cloc] = (short)f2bf(e);
          rsum[mi][r] += e;
        }
      }
    }
#pragma unroll
    for (int mi = 0; mi < 4; ++mi)
#pragma unroll
      for (int r = 0; r < 4; ++r) {
        float s = rsum[mi][r];
        s += __shfl_xor(s, 1);
        s += __shfl_xor(s, 2);
        s += __shfl_xor(s, 4);
        s += __shfl_xor(s, 8);
        if (t16 == 0)
          atomicAdd(&den[mBase + wy * 64 + mi * 16 + quad * 4 + r], s);
      }
    __syncthreads();
    // coalesced non-temporal store: 8 iters x 256 thr x 16 B = 32 KB tile
    int rr = tid >> 4;            // 0..15
    int c8 = (tid & 15) * 8;      // 0..120
#pragma unroll
    for (int i = 0; i < 8; ++i) {
      int row = i * 16 + rr;
      bf16x8 v = *(const bf16x8*)&smem[row * PSTRIDE + c8];
      __builtin_nontemporal_store(v, (bf16x8*)&Pout[(size_t)(mBase + row) * ldp + nBase + c8]);
    }
  } else if (mode == 1) {
#pragma unroll
    for (int mi = 0; mi < 4; ++mi) {
      long row = mBase + wy * 64 + mi * 16 + quad * 4;
#pragma unroll
      for (int ni = 0; ni < 4; ++ni) {
        long col = nBase + wx * 64 + ni * 16 + t16;
#pragma unroll
        for (int r = 0; r < 4; ++r) {
          size_t idx = (size_t)(row + r) * 1024 + col;
          atomicAdd(&Cacc[idx], acc[mi][ni][r]);
        }
      }
    }
  } else {
#pragma unroll
    for (int mi = 0; mi < 4; ++mi) {
      long row = mBase + wy * 64 + mi * 16 + quad * 4;
#pragma unroll
      for (int ni = 0; ni < 4; ++ni) {
        long col = nBase + wx * 64 + ni * 16 + t16;
#pragma unroll
        for (int r = 0; r < 4; ++r) {
          size_t idx = (size_t)(row + r) * 1024 + col;
          Cout[idx] = acc[mi][ni][r] + bias[col] + resid[idx];
        }
      }
    }
  }
}

// ---------------------------------------------------------------------------
// reprog_bf16 = bf16(num / den[row]); 4 elems/thread, 4 | 1024 so row uniform
__global__ void k_div(const float* __restrict__ num, const float* __restrict__ den,
                      short* __restrict__ out) {
  int i = (blockIdx.x * 256 + threadIdx.x) * 4;
  float4 v = *(const float4*)(num + i);
  float inv = 1.0f / den[i >> 10];
  ushort4 u;
  u.x = f2bf(v.x * inv); u.y = f2bf(v.y * inv);
  u.z = f2bf(v.z * inv); u.w = f2bf(v.w * inv);
  *(ushort4*)(out + i) = u;
}

// ---------------------------------------------------------------------------
// per-row LayerNorm over 1024 cols; one block (256 thr) per row
__global__ __launch_bounds__(256) void k_ln(const float* __restrict__ x,
                                            const float* __restrict__ gamma,
                                            const float* __restrict__ beta,
                                            float* __restrict__ out) {
  __shared__ float s_sum[4], s_sq[4];
  int row = blockIdx.x;
  int tid = threadIdx.x;
  const float* xr = x + (size_t)row * 1024;
  float4 v = *(const float4*)(xr + tid * 4);
  float s = v.x + v.y + v.z + v.w;
  float q = v.x * v.x + v.y * v.y + v.z * v.z + v.w * v.w;
#pragma unroll
  for (int off = 32; off >= 1; off >>= 1) {
    s += __shfl_down(s, off);
    q += __shfl_down(q, off);
  }
  int wv = tid >> 6;
  if ((tid & 63) == 0) { s_sum[wv] = s; s_sq[wv] = q; }
  __syncthreads();
  float tot  = s_sum[0] + s_sum[1] + s_sum[2] + s_sum[3];
  float totq = s_sq[0] + s_sq[1] + s_sq[2] + s_sq[3];
  float mu   = tot * (1.0f / 1024.0f);
  float var  = totq * (1.0f / 1024.0f) - mu * mu;
  float rstd = rsqrtf(var + 1e-5f);
  float4 g = *(const float4*)(gamma + tid * 4);
  float4 b = *(const float4*)(beta + tid * 4);
  float4 o;
  o.x = (v.x - mu) * rstd * g.x + b.x;
  o.y = (v.y - mu) * rstd * g.y + b.y;
  o.z = (v.z - mu) * rstd * g.z + b.z;
  o.w = (v.w - mu) * rstd * g.w + b.w;
  *(float4*)(out + (size_t)row * 1024 + tid * 4) = o;
}

// ---------------------------------------------------------------------------
extern "C" void kernel_launch(void* const* d_in, const int* in_sizes, int n_in,
                              void* d_out, int out_size, void* d_ws, size_t ws_size,
                              hipStream_t stream) {
  const float* patch = (const float*)d_in[0];   // [16,256,1024] = [4096,1024]
  const float* proto = (const float*)d_in[1];   // [32000,1024]
  const float* W     = (const float*)d_in[2];   // [1024,1024] (e-major, d-contig)
  const float* bvec  = (const float*)d_in[3];   // [1024]
  const float* gamma = (const float*)d_in[4];   // [1024]
  const float* beta  = (const float*)d_in[5];   // [1024]
  float* out = (float*)d_out;

  char* ws = (char*)d_ws;
  size_t off = 0;
  short* Q   = (short*)(ws + off); off += (size_t)ROWS * D_DIM * 2;     //   8 MB bf16 Q
  short* Kb  = (short*)(ws + off); off += (size_t)VOCAB * D_DIM * 2;    //  64 MB bf16 K [v][d]
  short* KT  = (short*)(ws + off); off += (size_t)VOCAB * D_DIM * 2;    //  64 MB bf16 K^T [d][v]
  short* Wb  = (short*)(ws + off); off += (size_t)D_DIM * D_DIM * 2;    //   2 MB bf16 W
  short* P   = (short*)(ws + off); off += (size_t)ROWS * VOCAB * 2;     // 262 MB bf16 P (full)
  float* num = (float*)(ws + off); off += (size_t)ROWS * D_DIM * 4;     //  16 MB fp32 numerator
  float* den = (float*)(ws + off); off += (size_t)ROWS * 4;             //  16 KB fp32 denominator
  float* pre = (float*)P;   // reuse P region for pre-LN buffer
  short* Rb  = Q;           // reuse Q region for reprogrammed bf16

  hipMemsetAsync(den, 0, ROWS * sizeof(float), stream);
  hipMemsetAsync(num, 0, (size_t)ROWS * D_DIM * sizeof(float), stream);

  k_cvt<<<ROWS * D_DIM / 4 / 256, 256, 0, stream>>>(patch, Q, ROWS * D_DIM / 4);
  k_cvt<<<D_DIM * D_DIM / 4 / 256, 256, 0, stream>>>(W, Wb, D_DIM * D_DIM / 4);
  k_prep_K<<<dim3(VOCAB / 32, D_DIM / 32), dim3(32, 8), 0, stream>>>(proto, Kb, KT, VOCAB, D_DIM);

  // P = exp(Q @ K^T), den += rowsum — M=4096 N=32000 K=1024, one dispatch.
  // grid x = M-tiles (fast): concurrent blocks share Q + a 32-tile K stripe.
  k_gemm<<<dim3(ROWS / 128, VOCAB / 128, 1), 256, 0, stream>>>(
      Q, D_DIM, Kb, D_DIM, D_DIM, 0,
      P, (long)VOCAB, den, nullptr, nullptr, nullptr, nullptr);

  // num += P @ K — M=4096 N=1024 K=32000, split-K=5 (100 BK-iters/block)
  k_gemm<<<dim3(D_DIM / 128, ROWS / 128, KSPLIT2), 256, 0, stream>>>(
      P, VOCAB, KT, VOCAB, VOCAB / KSPLIT2, 1,
      nullptr, 0, nullptr, num, nullptr, nullptr, nullptr);

  k_div<<<ROWS * D_DIM / 4 / 256, 256, 0, stream>>>(num, den, Rb);

  // pre = reprog @ W^T + b + patch — M=4096 N=1024 K=1024
  k_gemm<<<dim3(D_DIM / 128, ROWS / 128, 1), 256, 0, stream>>>(
      Rb, D_DIM, Wb, D_DIM, D_DIM, 2,
      nullptr, 0, nullptr, nullptr, bvec, patch, pre);

  k_ln<<<ROWS, 256, 0, stream>>>(pre, gamma, beta, out);
}

// Round 6
// 891.539 us; speedup vs baseline: 1.7876x; 1.3342x over previous
//
#include <hip/hip_runtime.h>
#include <hip/hip_bf16.h>
#include <cstdint>
#include <cstddef>

#define D_DIM 1024
#define VOCAB 32000
#define ROWS  4096      // 16*256
#define KSPLIT2 5       // GEMM2 split-K: 32000/5 = 6400/block = 50 BK128-iters

typedef __attribute__((ext_vector_type(8))) short bf16x8;   // 8 bf16 (MFMA A/B frag)
typedef __attribute__((ext_vector_type(4))) float f32x4;    // MFMA C/D frag
typedef __attribute__((ext_vector_type(4))) unsigned int u32x4;  // 16B (nt-store-able)

// float -> bf16 bits, round-to-nearest-even
static __device__ __forceinline__ unsigned short f2bf(float f) {
  union { float f; unsigned int u; } c; c.f = f;
  unsigned int u = c.u;
  u += 0x7fffu + ((u >> 16) & 1u);
  return (unsigned short)(u >> 16);
}

// pack two floats -> two fp8 e4m3 bytes (low 16 bits of result)
static __device__ __forceinline__ int pk8(float a, float b) {
  return __builtin_amdgcn_cvt_pk_fp8_f32(a, b, 0, false);
}

// async global->LDS, 16B per lane. LDS base wave-uniform; data lands at base + lane*16.
static __device__ __forceinline__ void gload_lds16(const void* g, void* s) {
  __builtin_amdgcn_global_load_lds(
      (const __attribute__((address_space(1))) uint32_t*)(g),
      (__attribute__((address_space(3))) uint32_t*)(s), 16, 0, 0);
}

// ---------------------------------------------------------------------------
// fp32 -> bf16 convert (4 elems/thread) — used for W only
__global__ void k_cvt(const float* __restrict__ src, short* __restrict__ dst, int n4) {
  int i = blockIdx.x * 256 + threadIdx.x;
  if (i < n4) {
    float4 v = *(const float4*)(src + (size_t)i * 4);
    ushort4 u;
    u.x = f2bf(v.x); u.y = f2bf(v.y); u.z = f2bf(v.z); u.w = f2bf(v.w);
    *(ushort4*)(dst + (size_t)i * 4) = u;
  }
}

// ---------------------------------------------------------------------------
// patch fp32 -> Q fp8 e4m3 (unscaled; |patch| ~ N(0,1) fits), 8 elems/thread
__global__ void k_cvt_q8(const float* __restrict__ src, uint8_t* __restrict__ dst) {
  int i = blockIdx.x * 256 + threadIdx.x;
  float4 a = *(const float4*)(src + (size_t)i * 8);
  float4 b = *(const float4*)(src + (size_t)i * 8 + 4);
  uint2 o;
  o.x = (pk8(a.x, a.y) & 0xffff) | (pk8(a.z, a.w) << 16);
  o.y = (pk8(b.x, b.y) & 0xffff) | (pk8(b.z, b.w) << 16);
  *(uint2*)(dst + (size_t)i * 8) = o;
}

// ---------------------------------------------------------------------------
// fused: proto fp32 [R][C] -> Kb fp8 [R][C] (x64) AND KT fp8 [C][R] (x64), one read
__global__ void k_prep_K8(const float* __restrict__ src, uint8_t* __restrict__ kb,
                          uint8_t* __restrict__ kt, int R, int C) {
  __shared__ uint8_t tile[64][68];
  int t  = threadIdx.x;           // 0..255
  int r0 = blockIdx.x * 64;       // v block
  int c0 = blockIdx.y * 64;       // d block
  int lr = t >> 4;                // 0..15
  int lc = (t & 15) * 4;          // 0..60
#pragma unroll
  for (int i = 0; i < 4; ++i) {
    int r = lr + 16 * i;
    float4 v = *(const float4*)(src + (size_t)(r0 + r) * C + c0 + lc);
    unsigned p = (pk8(v.x * 64.f, v.y * 64.f) & 0xffff) | (pk8(v.z * 64.f, v.w * 64.f) << 16);
    *(unsigned*)&tile[r][lc] = p;
    *(unsigned*)(kb + (size_t)(r0 + r) * C + c0 + lc) = p;
  }
  __syncthreads();
#pragma unroll
  for (int i = 0; i < 4; ++i) {
    int c = lr + 16 * i;          // d within tile
    unsigned p = tile[lc + 0][c] | (tile[lc + 1][c] << 8) |
                 (tile[lc + 2][c] << 16) | ((unsigned)tile[lc + 3][c] << 24);
    *(unsigned*)(kt + (size_t)(c0 + c) * R + r0 + lc) = p;
  }
}

// ---------------------------------------------------------------------------
// fp8 GEMM, C[M x N] = A[M x K] * B^T, B stored [N x K] k-contiguous, all fp8 e4m3.
// 128x128 tile, BK=128 bytes, 256 threads, 4 waves x (4x4) 16x16x32 fp8 MFMA.
// XOR-swizzled LDS (16B chunks): LDS[r][c] = global[r][c ^ (r&7)].
// mode 0 (GEMM1): grid x = M-tile (fast). acc holds 64*sims; e = exp(acc/64);
//                 P tile -> LDS -> coalesced 16B NON-TEMPORAL fp8 stores;
//                 den[row] += rowsum(e) (exact fp32, atomic).
// mode 1 (GEMM2): num[row*1024+col] += C (fp32 atomicAdd, split-K safe).
#define PS8 144   // P-tile LDS row stride, bytes (16B-aligned)
__global__ __launch_bounds__(256) void k_gemm8(
    const uint8_t* __restrict__ A, int lda,
    const uint8_t* __restrict__ B, int ldb,
    int Kdim, int mode,
    uint8_t* __restrict__ Pout, long ldp, float* __restrict__ den,
    float* __restrict__ Cacc)
{
  __shared__ uint8_t smem[32768];     // As [0,16K), Bs [16K,32K); mode-0 epilogue
  uint8_t* As = smem;                 // reuses [0, 128*PS8) as fp8 P-tile
  uint8_t* Bs = smem + 16384;

  int tid  = threadIdx.x;
  int wave = tid >> 6;
  int lane = tid & 63;
  int quad = lane >> 4;
  int t16  = lane & 15;
  int wy = wave >> 1, wx = wave & 1;

  long mBase, nBase;
  if (mode == 0) { mBase = (long)blockIdx.x * 128; nBase = (long)blockIdx.y * 128; }
  else           { mBase = (long)blockIdx.y * 128; nBase = (long)blockIdx.x * 128; }
  int k0 = blockIdx.z * Kdim;

  const uint8_t* Ab = A + (size_t)mBase * lda + k0;
  const uint8_t* Bb = B + (size_t)nBase * ldb + k0;
  int lrow = lane >> 3;                      // 0..7
  int lcol = ((lane & 7) ^ lrow) * 16;       // swizzled source 16B chunk (bytes)

  f32x4 acc[4][4];
#pragma unroll
  for (int i = 0; i < 4; ++i)
#pragma unroll
    for (int j = 0; j < 4; ++j) acc[i][j] = (f32x4){0.f, 0.f, 0.f, 0.f};

  int sw = t16 & 7;

  for (int kk = 0; kk < Kdim; kk += 128) {
#pragma unroll
    for (int i = 0; i < 4; ++i) {
      int row = wave * 32 + i * 8;
      gload_lds16(Ab + (size_t)(row + lrow) * lda + kk + lcol, &As[row * 128]);
      gload_lds16(Bb + (size_t)(row + lrow) * ldb + kk + lcol, &Bs[row * 128]);
    }
    __syncthreads();
#pragma unroll
    for (int s = 0; s < 4; ++s) {            // k-step: 32 fp8 per mfma
      long af[4], bfr[4];
      int co = ((((s << 1) + (quad >> 1)) ^ sw) << 4) + ((quad & 1) << 3);
#pragma unroll
      for (int mi = 0; mi < 4; ++mi)
        af[mi] = *(const long*)&As[(wy * 64 + mi * 16 + t16) * 128 + co];
#pragma unroll
      for (int ni = 0; ni < 4; ++ni)
        bfr[ni] = *(const long*)&Bs[(wx * 64 + ni * 16 + t16) * 128 + co];
#pragma unroll
      for (int mi = 0; mi < 4; ++mi)
#pragma unroll
        for (int ni = 0; ni < 4; ++ni)
          acc[mi][ni] = __builtin_amdgcn_mfma_f32_16x16x32_fp8_fp8(
              af[mi], bfr[ni], acc[mi][ni], 0, 0, 0);
    }
    __syncthreads();
  }

  // epilogue. C/D: row = quad*4 + r, col = t16 within each 16x16 tile
  if (mode == 0) {
    float rsum[4][4];
#pragma unroll
    for (int mi = 0; mi < 4; ++mi)
#pragma unroll
      for (int r = 0; r < 4; ++r) rsum[mi][r] = 0.f;
#pragma unroll
    for (int mi = 0; mi < 4; ++mi) {
      int rloc = wy * 64 + mi * 16 + quad * 4;
#pragma unroll
      for (int ni = 0; ni < 4; ++ni) {
        int cloc = wx * 64 + ni * 16 + t16;
#pragma unroll
        for (int r = 0; r < 4; ++r) {
          float e = __expf(acc[mi][ni][r] * 0.015625f);   // undo K x64 scale
          smem[(rloc + r) * PS8 + cloc] = (uint8_t)pk8(e, e);
          rsum[mi][r] += e;
        }
      }
    }
#pragma unroll
    for (int mi = 0; mi < 4; ++mi)
#pragma unroll
      for (int r = 0; r < 4; ++r) {
        float s = rsum[mi][r];
        s += __shfl_xor(s, 1);
        s += __shfl_xor(s, 2);
        s += __shfl_xor(s, 4);
        s += __shfl_xor(s, 8);
        if (t16 == 0)
          atomicAdd(&den[mBase + wy * 64 + mi * 16 + quad * 4 + r], s);
      }
    __syncthreads();
    // coalesced nt store: 4 iters x 256 thr x 16 B = 16 KB fp8 tile
    int rr  = tid >> 3;            // 0..31
    int c16 = (tid & 7) * 16;      // 0..112
#pragma unroll
    for (int i = 0; i < 4; ++i) {
      int row = i * 32 + rr;
      u32x4 v = *(const u32x4*)&smem[row * PS8 + c16];
      __builtin_nontemporal_store(v, (u32x4*)&Pout[(size_t)(mBase + row) * ldp + nBase + c16]);
    }
  } else {
#pragma unroll
    for (int mi = 0; mi < 4; ++mi) {
      long row = mBase + wy * 64 + mi * 16 + quad * 4;
#pragma unroll
      for (int ni = 0; ni < 4; ++ni) {
        long col = nBase + wx * 64 + ni * 16 + t16;
#pragma unroll
        for (int r = 0; r < 4; ++r)
          atomicAdd(&Cacc[(size_t)(row + r) * 1024 + col], acc[mi][ni][r]);
      }
    }
  }
}

// ---------------------------------------------------------------------------
// bf16 GEMM for GEMM3 only: Cout = A@B^T + bias[col] + resid (128x128 tile, BK=64)
__global__ __launch_bounds__(256) void k_gemm_bf(
    const short* __restrict__ A, int lda,
    const short* __restrict__ B, int ldb, int Kdim,
    const float* __restrict__ bias, const float* __restrict__ resid,
    float* __restrict__ Cout)
{
  __shared__ short smem[16384];
  short* As = smem;
  short* Bs = smem + 8192;

  int tid  = threadIdx.x;
  int wave = tid >> 6;
  int lane = tid & 63;
  int quad = lane >> 4;
  int t16  = lane & 15;
  int wy = wave >> 1, wx = wave & 1;

  long mBase = (long)blockIdx.y * 128;
  long nBase = (long)blockIdx.x * 128;

  const short* Ab = A + (size_t)mBase * lda;
  const short* Bb = B + (size_t)nBase * ldb;
  int lrow = lane >> 3;
  int lcol = ((lane & 7) ^ lrow) * 8;

  f32x4 acc[4][4];
#pragma unroll
  for (int i = 0; i < 4; ++i)
#pragma unroll
    for (int j = 0; j < 4; ++j) acc[i][j] = (f32x4){0.f, 0.f, 0.f, 0.f};

  int sw = t16 & 7;

  for (int kk = 0; kk < Kdim; kk += 64) {
#pragma unroll
    for (int i = 0; i < 4; ++i) {
      int row = wave * 32 + i * 8;
      gload_lds16(Ab + (size_t)(row + lrow) * lda + kk + lcol, &As[row * 64]);
      gload_lds16(Bb + (size_t)(row + lrow) * ldb + kk + lcol, &Bs[row * 64]);
    }
    __syncthreads();
#pragma unroll
    for (int kc = 0; kc < 8; kc += 4) {
      bf16x8 af[4], bfr[4];
#pragma unroll
      for (int mi = 0; mi < 4; ++mi)
        af[mi] = *(const bf16x8*)&As[(wy * 64 + mi * 16 + t16) * 64 +
                                     (((kc + quad) ^ sw) << 3)];
#pragma unroll
      for (int ni = 0; ni < 4; ++ni)
        bfr[ni] = *(const bf16x8*)&Bs[(wx * 64 + ni * 16 + t16) * 64 +
                                      (((kc + quad) ^ sw) << 3)];
#pragma unroll
      for (int mi = 0; mi < 4; ++mi)
#pragma unroll
        for (int ni = 0; ni < 4; ++ni)
          acc[mi][ni] = __builtin_amdgcn_mfma_f32_16x16x32_bf16(af[mi], bfr[ni],
                                                                acc[mi][ni], 0, 0, 0);
    }
    __syncthreads();
  }

#pragma unroll
  for (int mi = 0; mi < 4; ++mi) {
    long row = mBase + wy * 64 + mi * 16 + quad * 4;
#pragma unroll
    for (int ni = 0; ni < 4; ++ni) {
      long col = nBase + wx * 64 + ni * 16 + t16;
#pragma unroll
      for (int r = 0; r < 4; ++r) {
        size_t idx = (size_t)(row + r) * 1024 + col;
        Cout[idx] = acc[mi][ni][r] + bias[col] + resid[idx];
      }
    }
  }
}

// ---------------------------------------------------------------------------
// reprog_bf16 = bf16(num / (64*den[row]))  (undo K x64 scale in GEMM2 output)
__global__ void k_div(const float* __restrict__ num, const float* __restrict__ den,
                      short* __restrict__ out) {
  int i = (blockIdx.x * 256 + threadIdx.x) * 4;
  float4 v = *(const float4*)(num + i);
  float inv = 0.015625f / den[i >> 10];
  ushort4 u;
  u.x = f2bf(v.x * inv); u.y = f2bf(v.y * inv);
  u.z = f2bf(v.z * inv); u.w = f2bf(v.w * inv);
  *(ushort4*)(out + i) = u;
}

// ---------------------------------------------------------------------------
// per-row LayerNorm over 1024 cols; one block (256 thr) per row
__global__ __launch_bounds__(256) void k_ln(const float* __restrict__ x,
                                            const float* __restrict__ gamma,
                                            const float* __restrict__ beta,
                                            float* __restrict__ out) {
  __shared__ float s_sum[4], s_sq[4];
  int row = blockIdx.x;
  int tid = threadIdx.x;
  const float* xr = x + (size_t)row * 1024;
  float4 v = *(const float4*)(xr + tid * 4);
  float s = v.x + v.y + v.z + v.w;
  float q = v.x * v.x + v.y * v.y + v.z * v.z + v.w * v.w;
#pragma unroll
  for (int off = 32; off >= 1; off >>= 1) {
    s += __shfl_down(s, off);
    q += __shfl_down(q, off);
  }
  int wv = tid >> 6;
  if ((tid & 63) == 0) { s_sum[wv] = s; s_sq[wv] = q; }
  __syncthreads();
  float tot  = s_sum[0] + s_sum[1] + s_sum[2] + s_sum[3];
  float totq = s_sq[0] + s_sq[1] + s_sq[2] + s_sq[3];
  float mu   = tot * (1.0f / 1024.0f);
  float var  = totq * (1.0f / 1024.0f) - mu * mu;
  float rstd = rsqrtf(var + 1e-5f);
  float4 g = *(const float4*)(gamma + tid * 4);
  float4 b = *(const float4*)(beta + tid * 4);
  float4 o;
  o.x = (v.x - mu) * rstd * g.x + b.x;
  o.y = (v.y - mu) * rstd * g.y + b.y;
  o.z = (v.z - mu) * rstd * g.z + b.z;
  o.w = (v.w - mu) * rstd * g.w + b.w;
  *(float4*)(out + (size_t)row * 1024 + tid * 4) = o;
}

// ---------------------------------------------------------------------------
extern "C" void kernel_launch(void* const* d_in, const int* in_sizes, int n_in,
                              void* d_out, int out_size, void* d_ws, size_t ws_size,
                              hipStream_t stream) {
  const float* patch = (const float*)d_in[0];   // [4096,1024]
  const float* proto = (const float*)d_in[1];   // [32000,1024]
  const float* W     = (const float*)d_in[2];   // [1024,1024]
  const float* bvec  = (const float*)d_in[3];
  const float* gamma = (const float*)d_in[4];
  const float* beta  = (const float*)d_in[5];
  float* out = (float*)d_out;

  char* ws = (char*)d_ws;
  size_t off = 0;
  uint8_t* Q8  = (uint8_t*)(ws + off); off += (size_t)ROWS * D_DIM;      //   4 MB fp8 Q
  uint8_t* Kb8 = (uint8_t*)(ws + off); off += (size_t)VOCAB * D_DIM;     //  32 MB fp8 K (x64)
  uint8_t* KT8 = (uint8_t*)(ws + off); off += (size_t)VOCAB * D_DIM;     //  32 MB fp8 K^T (x64)
  short*   Wb  = (short*)(ws + off);   off += (size_t)D_DIM * D_DIM * 2; //   2 MB bf16 W
  short*   Rb  = (short*)(ws + off);   off += (size_t)ROWS * D_DIM * 2;  //   8 MB bf16 reprog
  uint8_t* P8  = (uint8_t*)(ws + off); off += (size_t)ROWS * VOCAB;      // 131 MB fp8 P
  float*   num = (float*)(ws + off);   off += (size_t)ROWS * D_DIM * 4;  //  16 MB fp32 num
  float*   den = (float*)(ws + off);   off += (size_t)ROWS * 4;          //  16 KB fp32 den
  float*   pre = (float*)P8;   // reuse P region for pre-LN buffer (16 MB << 131 MB)

  hipMemsetAsync(den, 0, ROWS * sizeof(float), stream);
  hipMemsetAsync(num, 0, (size_t)ROWS * D_DIM * sizeof(float), stream);

  k_cvt_q8<<<ROWS * D_DIM / 8 / 256, 256, 0, stream>>>(patch, Q8);
  k_cvt<<<D_DIM * D_DIM / 4 / 256, 256, 0, stream>>>(W, Wb, D_DIM * D_DIM / 4);
  k_prep_K8<<<dim3(VOCAB / 64, D_DIM / 64), 256, 0, stream>>>(proto, Kb8, KT8, VOCAB, D_DIM);

  // GEMM1: P = exp(Q @ K^T), den += rowsum — M=4096 N=32000 K=1024 (fp8)
  k_gemm8<<<dim3(ROWS / 128, VOCAB / 128, 1), 256, 0, stream>>>(
      Q8, D_DIM, Kb8, D_DIM, D_DIM, 0,
      P8, (long)VOCAB, den, nullptr);

  // GEMM2: num += P @ K — M=4096 N=1024 K=32000, split-K=5 (fp8)
  k_gemm8<<<dim3(D_DIM / 128, ROWS / 128, KSPLIT2), 256, 0, stream>>>(
      P8, VOCAB, KT8, VOCAB, VOCAB / KSPLIT2, 1,
      nullptr, 0, nullptr, num);

  k_div<<<ROWS * D_DIM / 4 / 256, 256, 0, stream>>>(num, den, Rb);

  // GEMM3: pre = reprog @ W^T + b + patch — M=4096 N=1024 K=1024 (bf16)
  k_gemm_bf<<<dim3(D_DIM / 128, ROWS / 128), 256, 0, stream>>>(
      Rb, D_DIM, Wb, D_DIM, D_DIM, bvec, patch, pre);

  k_ln<<<ROWS, 256, 0, stream>>>(pre, gamma, beta, out);
}

// Round 7
// 683.666 us; speedup vs baseline: 2.3311x; 1.3041x over previous
//
#include <hip/hip_runtime.h>
#include <hip/hip_bf16.h>
#include <cstdint>
#include <cstddef>

#define D_DIM 1024
#define VOCAB 32000
#define ROWS  4096      // 16*256
#define KSPLIT2 5       // GEMM2 split-K: 32000/5 = 6400/block = 50 BK128-iters

typedef __attribute__((ext_vector_type(8))) short bf16x8;   // 8 bf16 (MFMA A/B frag)
typedef __attribute__((ext_vector_type(4))) float f32x4;    // MFMA C/D frag
typedef __attribute__((ext_vector_type(4))) int   i32x4;    // 16B LDS/global move
typedef __attribute__((ext_vector_type(8))) int   i32x8;    // fp8 K=128 A/B frag (8 VGPRs)

static __device__ __forceinline__ i32x8 cat8(i32x4 lo, i32x4 hi) {
  return __builtin_shufflevector(lo, hi, 0, 1, 2, 3, 4, 5, 6, 7);
}

// float -> bf16 bits, round-to-nearest-even
static __device__ __forceinline__ unsigned short f2bf(float f) {
  union { float f; unsigned int u; } c; c.f = f;
  unsigned int u = c.u;
  u += 0x7fffu + ((u >> 16) & 1u);
  return (unsigned short)(u >> 16);
}

// pack two floats -> two fp8 e4m3 bytes (low 16 bits of result)
static __device__ __forceinline__ int pk8(float a, float b) {
  return __builtin_amdgcn_cvt_pk_fp8_f32(a, b, 0, false);
}

// async global->LDS, 16B per lane. LDS base wave-uniform; data lands at base + lane*16.
static __device__ __forceinline__ void gload_lds16(const void* g, void* s) {
  __builtin_amdgcn_global_load_lds(
      (const __attribute__((address_space(1))) uint32_t*)(g),
      (__attribute__((address_space(3))) uint32_t*)(s), 16, 0, 0);
}

// ---------------------------------------------------------------------------
// fp32 -> bf16 convert (4 elems/thread) — used for W only
__global__ void k_cvt(const float* __restrict__ src, short* __restrict__ dst, int n4) {
  int i = blockIdx.x * 256 + threadIdx.x;
  if (i < n4) {
    float4 v = *(const float4*)(src + (size_t)i * 4);
    ushort4 u;
    u.x = f2bf(v.x); u.y = f2bf(v.y); u.z = f2bf(v.z); u.w = f2bf(v.w);
    *(ushort4*)(dst + (size_t)i * 4) = u;
  }
}

// ---------------------------------------------------------------------------
// patch fp32 -> Q fp8 e4m3 (unscaled; |patch| ~ N(0,1) fits), 8 elems/thread
__global__ void k_cvt_q8(const float* __restrict__ src, uint8_t* __restrict__ dst) {
  int i = blockIdx.x * 256 + threadIdx.x;
  float4 a = *(const float4*)(src + (size_t)i * 8);
  float4 b = *(const float4*)(src + (size_t)i * 8 + 4);
  uint2 o;
  o.x = (pk8(a.x, a.y) & 0xffff) | (pk8(a.z, a.w) << 16);
  o.y = (pk8(b.x, b.y) & 0xffff) | (pk8(b.z, b.w) << 16);
  *(uint2*)(dst + (size_t)i * 8) = o;
}

// ---------------------------------------------------------------------------
// fused: proto fp32 [R][C] -> Kb fp8 [R][C] (x64) AND KT fp8 [C][R] (x64), one read
__global__ void k_prep_K8(const float* __restrict__ src, uint8_t* __restrict__ kb,
                          uint8_t* __restrict__ kt, int R, int C) {
  __shared__ uint8_t tile[64][68];
  int t  = threadIdx.x;           // 0..255
  int r0 = blockIdx.x * 64;       // v block
  int c0 = blockIdx.y * 64;       // d block
  int lr = t >> 4;                // 0..15
  int lc = (t & 15) * 4;          // 0..60
#pragma unroll
  for (int i = 0; i < 4; ++i) {
    int r = lr + 16 * i;
    float4 v = *(const float4*)(src + (size_t)(r0 + r) * C + c0 + lc);
    unsigned p = (pk8(v.x * 64.f, v.y * 64.f) & 0xffff) | (pk8(v.z * 64.f, v.w * 64.f) << 16);
    *(unsigned*)&tile[r][lc] = p;
    *(unsigned*)(kb + (size_t)(r0 + r) * C + c0 + lc) = p;
  }
  __syncthreads();
#pragma unroll
  for (int i = 0; i < 4; ++i) {
    int c = lr + 16 * i;          // d within tile
    unsigned p = tile[lc + 0][c] | (tile[lc + 1][c] << 8) |
                 (tile[lc + 2][c] << 16) | ((unsigned)tile[lc + 3][c] << 24);
    *(unsigned*)(kt + (size_t)(c0 + c) * R + r0 + lc) = p;
  }
}

// ---------------------------------------------------------------------------
// fp8 GEMM, C[M x N] = A[M x K] * B^T, B stored [N x K] k-contiguous, all fp8 e4m3.
// 128x128 tile, BK=128 bytes, 256 threads, 4 waves x (4x4) MFMA tiles.
// K-loop: ONE mfma_scale_f32_16x16x128_f8f6f4 per (mi,ni) per BK-iter (identity
// E8M0 scales = 0x7F -> 2^0), fed by two ds_read_b128 per fragment. XOR-swizzled
// LDS (LDS[r][chunk c] = global[r][c ^ (r&7)]) spreads each 8-lane group over
// all 32 banks (2-way t16+-8 aliasing = free).
// mode 0 (GEMM1): grid x = M-tile (fast). acc holds 64*sims; e = exp(acc/64);
//                 P tile -> LDS -> coalesced 16B NON-TEMPORAL fp8 stores;
//                 den[row] += rowsum(e) (exact fp32, atomic).
// mode 1 (GEMM2): num[row*1024+col] += C (fp32 atomicAdd, split-K safe).
#define PS8 144   // P-tile LDS row stride, bytes (16B-aligned)
__global__ __launch_bounds__(256) void k_gemm8(
    const uint8_t* __restrict__ A, int lda,
    const uint8_t* __restrict__ B, int ldb,
    int Kdim, int mode,
    uint8_t* __restrict__ Pout, long ldp, float* __restrict__ den,
    float* __restrict__ Cacc)
{
  __shared__ uint8_t smem[32768];     // As [0,16K), Bs [16K,32K); mode-0 epilogue
  uint8_t* As = smem;                 // reuses [0, 128*PS8) as fp8 P-tile
  uint8_t* Bs = smem + 16384;

  int tid  = threadIdx.x;
  int wave = tid >> 6;
  int lane = tid & 63;
  int quad = lane >> 4;
  int t16  = lane & 15;
  int wy = wave >> 1, wx = wave & 1;

  long mBase, nBase;
  if (mode == 0) { mBase = (long)blockIdx.x * 128; nBase = (long)blockIdx.y * 128; }
  else           { mBase = (long)blockIdx.y * 128; nBase = (long)blockIdx.x * 128; }
  int k0 = blockIdx.z * Kdim;

  const uint8_t* Ab = A + (size_t)mBase * lda + k0;
  const uint8_t* Bb = B + (size_t)nBase * ldb + k0;
  int lrow = lane >> 3;                      // 0..7
  int lcol = ((lane & 7) ^ lrow) * 16;       // swizzled source 16B chunk (bytes)

  f32x4 acc[4][4];
#pragma unroll
  for (int i = 0; i < 4; ++i)
#pragma unroll
    for (int j = 0; j < 4; ++j) acc[i][j] = (f32x4){0.f, 0.f, 0.f, 0.f};

  int sw = t16 & 7;
  // lane's k-range = [quad*32, quad*32+32) = global chunks 2q, 2q+1
  int co0 = (((quad << 1) ^ sw) << 4);       // LDS byte offset of global chunk 2q
  const int SC1 = 0x7F7F7F7F;                // identity E8M0 scales (2^0 per block)

  for (int kk = 0; kk < Kdim; kk += 128) {
#pragma unroll
    for (int i = 0; i < 4; ++i) {
      int row = wave * 32 + i * 8;
      gload_lds16(Ab + (size_t)(row + lrow) * lda + kk + lcol, &As[row * 128]);
      gload_lds16(Bb + (size_t)(row + lrow) * ldb + kk + lcol, &Bs[row * 128]);
    }
    __syncthreads();
    i32x8 af[4], bfr[4];
#pragma unroll
    for (int mi = 0; mi < 4; ++mi) {
      const uint8_t* rp = &As[(wy * 64 + mi * 16 + t16) * 128];
      af[mi] = cat8(*(const i32x4*)(rp + co0), *(const i32x4*)(rp + (co0 ^ 16)));
    }
#pragma unroll
    for (int ni = 0; ni < 4; ++ni) {
      const uint8_t* rp = &Bs[(wx * 64 + ni * 16 + t16) * 128];
      bfr[ni] = cat8(*(const i32x4*)(rp + co0), *(const i32x4*)(rp + (co0 ^ 16)));
    }
#pragma unroll
    for (int mi = 0; mi < 4; ++mi)
#pragma unroll
      for (int ni = 0; ni < 4; ++ni)
        acc[mi][ni] = __builtin_amdgcn_mfma_scale_f32_16x16x128_f8f6f4(
            af[mi], bfr[ni], acc[mi][ni], 0, 0, 0, SC1, 0, SC1);
    __syncthreads();
  }

  // epilogue. C/D: row = quad*4 + r, col = t16 within each 16x16 tile
  if (mode == 0) {
    float rsum[4][4];
#pragma unroll
    for (int mi = 0; mi < 4; ++mi)
#pragma unroll
      for (int r = 0; r < 4; ++r) rsum[mi][r] = 0.f;
#pragma unroll
    for (int mi = 0; mi < 4; ++mi) {
      int rloc = wy * 64 + mi * 16 + quad * 4;
#pragma unroll
      for (int ni = 0; ni < 4; ++ni) {
        int cloc = wx * 64 + ni * 16 + t16;
#pragma unroll
        for (int r = 0; r < 4; ++r) {
          float e = __expf(acc[mi][ni][r] * 0.015625f);   // undo K x64 scale
          smem[(rloc + r) * PS8 + cloc] = (uint8_t)pk8(e, e);
          rsum[mi][r] += e;
        }
      }
    }
#pragma unroll
    for (int mi = 0; mi < 4; ++mi)
#pragma unroll
      for (int r = 0; r < 4; ++r) {
        float s = rsum[mi][r];
        s += __shfl_xor(s, 1);
        s += __shfl_xor(s, 2);
        s += __shfl_xor(s, 4);
        s += __shfl_xor(s, 8);
        if (t16 == 0)
          atomicAdd(&den[mBase + wy * 64 + mi * 16 + quad * 4 + r], s);
      }
    __syncthreads();
    // coalesced nt store: 4 iters x 256 thr x 16 B = 16 KB fp8 tile
    int rr  = tid >> 3;            // 0..31
    int c16 = (tid & 7) * 16;      // 0..112
#pragma unroll
    for (int i = 0; i < 4; ++i) {
      int row = i * 32 + rr;
      i32x4 v = *(const i32x4*)&smem[row * PS8 + c16];
      __builtin_nontemporal_store(v, (i32x4*)&Pout[(size_t)(mBase + row) * ldp + nBase + c16]);
    }
  } else {
#pragma unroll
    for (int mi = 0; mi < 4; ++mi) {
      long row = mBase + wy * 64 + mi * 16 + quad * 4;
#pragma unroll
      for (int ni = 0; ni < 4; ++ni) {
        long col = nBase + wx * 64 + ni * 16 + t16;
#pragma unroll
        for (int r = 0; r < 4; ++r)
          atomicAdd(&Cacc[(size_t)(row + r) * 1024 + col], acc[mi][ni][r]);
      }
    }
  }
}

// ---------------------------------------------------------------------------
// bf16 GEMM for GEMM3 only: Cout = A@B^T + bias[col] + resid (128x128 tile, BK=64)
__global__ __launch_bounds__(256) void k_gemm_bf(
    const short* __restrict__ A, int lda,
    const short* __restrict__ B, int ldb, int Kdim,
    const float* __restrict__ bias, const float* __restrict__ resid,
    float* __restrict__ Cout)
{
  __shared__ short smem[16384];
  short* As = smem;
  short* Bs = smem + 8192;

  int tid  = threadIdx.x;
  int wave = tid >> 6;
  int lane = tid & 63;
  int quad = lane >> 4;
  int t16  = lane & 15;
  int wy = wave >> 1, wx = wave & 1;

  long mBase = (long)blockIdx.y * 128;
  long nBase = (long)blockIdx.x * 128;

  const short* Ab = A + (size_t)mBase * lda;
  const short* Bb = B + (size_t)nBase * ldb;
  int lrow = lane >> 3;
  int lcol = ((lane & 7) ^ lrow) * 8;

  f32x4 acc[4][4];
#pragma unroll
  for (int i = 0; i < 4; ++i)
#pragma unroll
    for (int j = 0; j < 4; ++j) acc[i][j] = (f32x4){0.f, 0.f, 0.f, 0.f};

  int sw = t16 & 7;

  for (int kk = 0; kk < Kdim; kk += 64) {
#pragma unroll
    for (int i = 0; i < 4; ++i) {
      int row = wave * 32 + i * 8;
      gload_lds16(Ab + (size_t)(row + lrow) * lda + kk + lcol, &As[row * 64]);
      gload_lds16(Bb + (size_t)(row + lrow) * ldb + kk + lcol, &Bs[row * 64]);
    }
    __syncthreads();
#pragma unroll
    for (int kc = 0; kc < 8; kc += 4) {
      bf16x8 af[4], bfr[4];
#pragma unroll
      for (int mi = 0; mi < 4; ++mi)
        af[mi] = *(const bf16x8*)&As[(wy * 64 + mi * 16 + t16) * 64 +
                                     (((kc + quad) ^ sw) << 3)];
#pragma unroll
      for (int ni = 0; ni < 4; ++ni)
        bfr[ni] = *(const bf16x8*)&Bs[(wx * 64 + ni * 16 + t16) * 64 +
                                      (((kc + quad) ^ sw) << 3)];
#pragma unroll
      for (int mi = 0; mi < 4; ++mi)
#pragma unroll
        for (int ni = 0; ni < 4; ++ni)
          acc[mi][ni] = __builtin_amdgcn_mfma_f32_16x16x32_bf16(af[mi], bfr[ni],
                                                                acc[mi][ni], 0, 0, 0);
    }
    __syncthreads();
  }

#pragma unroll
  for (int mi = 0; mi < 4; ++mi) {
    long row = mBase + wy * 64 + mi * 16 + quad * 4;
#pragma unroll
    for (int ni = 0; ni < 4; ++ni) {
      long col = nBase + wx * 64 + ni * 16 + t16;
#pragma unroll
      for (int r = 0; r < 4; ++r) {
        size_t idx = (size_t)(row + r) * 1024 + col;
        Cout[idx] = acc[mi][ni][r] + bias[col] + resid[idx];
      }
    }
  }
}

// ---------------------------------------------------------------------------
// reprog_bf16 = bf16(num / (64*den[row]))  (undo K x64 scale in GEMM2 output)
__global__ void k_div(const float* __restrict__ num, const float* __restrict__ den,
                      short* __restrict__ out) {
  int i = (blockIdx.x * 256 + threadIdx.x) * 4;
  float4 v = *(const float4*)(num + i);
  float inv = 0.015625f / den[i >> 10];
  ushort4 u;
  u.x = f2bf(v.x * inv); u.y = f2bf(v.y * inv);
  u.z = f2bf(v.z * inv); u.w = f2bf(v.w * inv);
  *(ushort4*)(out + i) = u;
}

// ---------------------------------------------------------------------------
// per-row LayerNorm over 1024 cols; one block (256 thr) per row
__global__ __launch_bounds__(256) void k_ln(const float* __restrict__ x,
                                            const float* __restrict__ gamma,
                                            const float* __restrict__ beta,
                                            float* __restrict__ out) {
  __shared__ float s_sum[4], s_sq[4];
  int row = blockIdx.x;
  int tid = threadIdx.x;
  const float* xr = x + (size_t)row * 1024;
  float4 v = *(const float4*)(xr + tid * 4);
  float s = v.x + v.y + v.z + v.w;
  float q = v.x * v.x + v.y * v.y + v.z * v.z + v.w * v.w;
#pragma unroll
  for (int off = 32; off >= 1; off >>= 1) {
    s += __shfl_down(s, off);
    q += __shfl_down(q, off);
  }
  int wv = tid >> 6;
  if ((tid & 63) == 0) { s_sum[wv] = s; s_sq[wv] = q; }
  __syncthreads();
  float tot  = s_sum[0] + s_sum[1] + s_sum[2] + s_sum[3];
  float totq = s_sq[0] + s_sq[1] + s_sq[2] + s_sq[3];
  float mu   = tot * (1.0f / 1024.0f);
  float var  = totq * (1.0f / 1024.0f) - mu * mu;
  float rstd = rsqrtf(var + 1e-5f);
  float4 g = *(const float4*)(gamma + tid * 4);
  float4 b = *(const float4*)(beta + tid * 4);
  float4 o;
  o.x = (v.x - mu) * rstd * g.x + b.x;
  o.y = (v.y - mu) * rstd * g.y + b.y;
  o.z = (v.z - mu) * rstd * g.z + b.z;
  o.w = (v.w - mu) * rstd * g.w + b.w;
  *(float4*)(out + (size_t)row * 1024 + tid * 4) = o;
}

// ---------------------------------------------------------------------------
extern "C" void kernel_launch(void* const* d_in, const int* in_sizes, int n_in,
                              void* d_out, int out_size, void* d_ws, size_t ws_size,
                              hipStream_t stream) {
  const float* patch = (const float*)d_in[0];   // [4096,1024]
  const float* proto = (const float*)d_in[1];   // [32000,1024]
  const float* W     = (const float*)d_in[2];   // [1024,1024]
  const float* bvec  = (const float*)d_in[3];
  const float* gamma = (const float*)d_in[4];
  const float* beta  = (const float*)d_in[5];
  float* out = (float*)d_out;

  char* ws = (char*)d_ws;
  size_t off = 0;
  uint8_t* Q8  = (uint8_t*)(ws + off); off += (size_t)ROWS * D_DIM;      //   4 MB fp8 Q
  uint8_t* Kb8 = (uint8_t*)(ws + off); off += (size_t)VOCAB * D_DIM;     //  32 MB fp8 K (x64)
  uint8_t* KT8 = (uint8_t*)(ws + off); off += (size_t)VOCAB * D_DIM;     //  32 MB fp8 K^T (x64)
  short*   Wb  = (short*)(ws + off);   off += (size_t)D_DIM * D_DIM * 2; //   2 MB bf16 W
  short*   Rb  = (short*)(ws + off);   off += (size_t)ROWS * D_DIM * 2;  //   8 MB bf16 reprog
  uint8_t* P8  = (uint8_t*)(ws + off); off += (size_t)ROWS * VOCAB;      // 131 MB fp8 P
  float*   num = (float*)(ws + off);   off += (size_t)ROWS * D_DIM * 4;  //  16 MB fp32 num
  float*   den = (float*)(ws + off);   off += (size_t)ROWS * 4;          //  16 KB fp32 den
  float*   pre = (float*)P8;   // reuse P region for pre-LN buffer (16 MB << 131 MB)

  hipMemsetAsync(den, 0, ROWS * sizeof(float), stream);
  hipMemsetAsync(num, 0, (size_t)ROWS * D_DIM * sizeof(float), stream);

  k_cvt_q8<<<ROWS * D_DIM / 8 / 256, 256, 0, stream>>>(patch, Q8);
  k_cvt<<<D_DIM * D_DIM / 4 / 256, 256, 0, stream>>>(W, Wb, D_DIM * D_DIM / 4);
  k_prep_K8<<<dim3(VOCAB / 64, D_DIM / 64), 256, 0, stream>>>(proto, Kb8, KT8, VOCAB, D_DIM);

  // GEMM1: P = exp(Q @ K^T), den += rowsum — M=4096 N=32000 K=1024 (fp8, K=128 MFMA)
  k_gemm8<<<dim3(ROWS / 128, VOCAB / 128, 1), 256, 0, stream>>>(
      Q8, D_DIM, Kb8, D_DIM, D_DIM, 0,
      P8, (long)VOCAB, den, nullptr);

  // GEMM2: num += P @ K — M=4096 N=1024 K=32000, split-K=5 (fp8, K=128 MFMA)
  k_gemm8<<<dim3(D_DIM / 128, ROWS / 128, KSPLIT2), 256, 0, stream>>>(
      P8, VOCAB, KT8, VOCAB, VOCAB / KSPLIT2, 1,
      nullptr, 0, nullptr, num);

  k_div<<<ROWS * D_DIM / 4 / 256, 256, 0, stream>>>(num, den, Rb);

  // GEMM3: pre = reprog @ W^T + b + patch — M=4096 N=1024 K=1024 (bf16)
  k_gemm_bf<<<dim3(D_DIM / 128, ROWS / 128), 256, 0, stream>>>(
      Rb, D_DIM, Wb, D_DIM, D_DIM, bvec, patch, pre);

  k_ln<<<ROWS, 256, 0, stream>>>(pre, gamma, beta, out);
}